// Round 13
// baseline (7872.602 us; speedup 1.0000x reference)
//
#include <hip/hip_runtime.h>
#include <hip/hip_bf16.h>

#define TT 2048
#define BB 256
#define HH 128
#define UDIM 16
#define YDIM 16
#define ZDIM 32
#define H3 384

typedef __hip_bfloat16 bf16;
typedef _Float16 half2v __attribute__((ext_vector_type(2)));

constexpr int clog2(int x) { return x <= 1 ? 0 : 1 + clog2(x >> 1); }

// ---------------------------------------------------------------------------
// f32 register-weight linear stage (phi_u only, unchanged).
// ---------------------------------------------------------------------------
template <int M_, int K_, int O_, bool RELU_>
__device__ __forceinline__ void rstage(const float* __restrict__ wfrag,
                                       const float* __restrict__ xin, int XS,
                                       float* __restrict__ ps,
                                       const float* __restrict__ bias,
                                       float* __restrict__ outb)
{
    constexpr int F = K_ / O_;
    const int T = threadIdx.x;
    const int jb = T & (M_ / 2 - 1);
    const int o  = T >> clog2(M_ / 2);
#pragma unroll
    for (int r = 0; r < 8; ++r) {
        float a0 = 0.f, a1 = 0.f;
#pragma unroll
        for (int g = 0; g < F; g += 4) {
            const float4 xv = *reinterpret_cast<const float4*>(&xin[r * XS + o * F + g]);
            a0 += xv.x * wfrag[g]     + xv.y * wfrag[g + 1]
                + xv.z * wfrag[g + 2] + xv.w * wfrag[g + 3];
            a1 += xv.x * wfrag[F + g]     + xv.y * wfrag[F + g + 1]
                + xv.z * wfrag[F + g + 2] + xv.w * wfrag[F + g + 3];
        }
        ps[r * 1024 + o * M_ + jb]           = a0;
        ps[r * 1024 + o * M_ + jb + M_ / 2]  = a1;
    }
    __syncthreads();
    for (int oi = T; oi < 8 * M_; oi += 512) {
        const int r = oi >> clog2(M_);
        const int j = oi & (M_ - 1);
        float s = bias[j];
#pragma unroll
        for (int o2 = 0; o2 < O_; ++o2) s += ps[r * 1024 + o2 * M_ + j];
        if (RELU_) s = fmaxf(s, 0.f);
        outb[r * M_ + j] = s;
    }
    __syncthreads();
}

template <int M_, int K_, int O_>
__device__ __forceinline__ void loadw(float* __restrict__ wfrag, const float* __restrict__ Wg)
{
    constexpr int F = K_ / O_;
    const int T = threadIdx.x;
    const int jb = T & (M_ / 2 - 1);
    const int o  = T >> clog2(M_ / 2);
#pragma unroll
    for (int h = 0; h < 2; ++h)
#pragma unroll
        for (int g = 0; g < F; g += 4)
            *reinterpret_cast<float4*>(&wfrag[h * F + g]) =
                *reinterpret_cast<const float4*>(&Wg[(jb + h * (M_ / 2)) * K_ + o * F + g]);
}

// ---------------------------------------------------------------------------
// Lane-mapped f16 stage (head): o = T & (O-1) lives in lane bits, jb = T>>LO.
// Partials reduced IN-WAVE via shfl_xor; o==0 writes bias/ReLU f16 output.
// One barrier per stage, no ps array. Column chunks interleaved at 8-half
// granularity (col = o*8 + s*8*O) so x-reads hit all 32 banks.
// ---------------------------------------------------------------------------
template <int M_, int K_, int O_>
__device__ __forceinline__ void loadw_s(half2v* __restrict__ wfrag, const float* __restrict__ Wg)
{
    constexpr int F = K_ / O_;
    constexpr int FH = F / 2;
    constexpr int LO = clog2(O_);
    const int T = threadIdx.x;
    const int o  = T & (O_ - 1);
    const int jb = T >> LO;
#pragma unroll
    for (int h = 0; h < 2; ++h) {
        const float* src = Wg + (size_t)(jb + h * (M_ / 2)) * K_;
        if constexpr (F >= 8) {
            constexpr int NS = F / 8;
#pragma unroll
            for (int s = 0; s < NS; ++s)
#pragma unroll
                for (int e = 0; e < 4; ++e) {
                    const float* p = src + o * 8 + s * (8 * O_) + 2 * e;
                    half2v v; v.x = (_Float16)p[0]; v.y = (_Float16)p[1];
                    wfrag[h * FH + s * 4 + e] = v;
                }
        } else {
#pragma unroll
            for (int e = 0; e < 2; ++e) {
                const float* p = src + o * 4 + 2 * e;
                half2v v; v.x = (_Float16)p[0]; v.y = (_Float16)p[1];
                wfrag[h * FH + e] = v;
            }
        }
    }
}

template <int M_, int K_, int O_, bool RELU_>
__device__ __forceinline__ void rstage_s(const half2v* __restrict__ wfrag,
                                         const _Float16* __restrict__ xin, int XS,
                                         const float* __restrict__ bias,
                                         _Float16* __restrict__ outb)
{
    constexpr int F = K_ / O_;
    constexpr int FH = F / 2;
    constexpr int LO = clog2(O_);
    const int T = threadIdx.x;
    const int o  = T & (O_ - 1);
    const int jb = T >> LO;
#pragma unroll
    for (int r = 0; r < 8; ++r) {
        float a0 = 0.f, a1 = 0.f;
        if constexpr (F >= 8) {
            constexpr int NS = F / 8;
#pragma unroll
            for (int s = 0; s < NS; ++s) {
                half2v xt[4];
                *reinterpret_cast<float4*>(xt) =
                    *reinterpret_cast<const float4*>(xin + r * XS + o * 8 + s * (8 * O_));
#pragma unroll
                for (int e = 0; e < 4; ++e) {
                    a0 = __builtin_amdgcn_fdot2(xt[e], wfrag[s * 4 + e], a0, false);
                    a1 = __builtin_amdgcn_fdot2(xt[e], wfrag[FH + s * 4 + e], a1, false);
                }
            }
        } else {   // F == 4
            half2v xt[2];
            *reinterpret_cast<float2*>(xt) =
                *reinterpret_cast<const float2*>(xin + r * XS + o * 4);
            a0 = __builtin_amdgcn_fdot2(xt[0], wfrag[0], a0, false);
            a0 = __builtin_amdgcn_fdot2(xt[1], wfrag[1], a0, false);
            a1 = __builtin_amdgcn_fdot2(xt[0], wfrag[FH], a1, false);
            a1 = __builtin_amdgcn_fdot2(xt[1], wfrag[FH + 1], a1, false);
        }
#pragma unroll
        for (int s = 1; s < O_; s <<= 1) {
            a0 += __shfl_xor(a0, s, 64);
            a1 += __shfl_xor(a1, s, 64);
        }
        if (o == 0) {
            float s0 = a0 + bias[jb];
            float s1 = a1 + bias[jb + M_ / 2];
            if (RELU_) { s0 = fmaxf(s0, 0.f); s1 = fmaxf(s1, 0.f); }
            outb[r * M_ + jb]          = (_Float16)s0;
            outb[r * M_ + jb + M_ / 2] = (_Float16)s1;
        }
    }
    __syncthreads();
}

// ---------------------------------------------------------------------------
// phi_u: register weights, persistent 512 blocks (unchanged).
// ---------------------------------------------------------------------------
__global__ __launch_bounds__(512, 2) void phi_u_kernel(
    const float* __restrict__ u, const float* __restrict__ w1, const float* __restrict__ b1,
    const float* __restrict__ w2, const float* __restrict__ b2,
    bf16* __restrict__ pu, int s0, int nrows)
{
    __shared__ __align__(16) float ps[8192];
    __shared__ __align__(16) float xc[8 * 16];
    __shared__ __align__(16) float bP[8 * 128];
    __shared__ __align__(16) float bias_l[256];
    const int T = threadIdx.x;
    if (T < 128) { bias_l[T] = b1[T]; bias_l[128 + T] = b2[T]; }
    const int jb = T & 63, o = T >> 6;
    float wa[4];
    wa[0] = w1[jb * 16 + o * 2];        wa[1] = w1[jb * 16 + o * 2 + 1];
    wa[2] = w1[(jb + 64) * 16 + o * 2]; wa[3] = w1[(jb + 64) * 16 + o * 2 + 1];
    float wb[32]; loadw<128, 128, 8>(wb, w2);
    __syncthreads();

    for (int tile = blockIdx.x; tile < nrows / 32; tile += gridDim.x) {
        const int n0 = tile * 32;
        const int b  = s0 + (n0 >> 11);
        const int t0 = n0 & (TT - 1);
#pragma unroll 1
        for (int rb = 0; rb < 4; ++rb) {
            if (T < 128) {
                const int r = T & 7, c = T >> 3;
                xc[r * 16 + c] = u[((size_t)b * UDIM + c) * TT + t0 + rb * 8 + r];
            }
            __syncthreads();
#pragma unroll
            for (int r = 0; r < 8; ++r) {
                const float x0 = xc[r * 16 + o * 2], x1 = xc[r * 16 + o * 2 + 1];
                ps[r * 1024 + o * 128 + jb]      = x0 * wa[0] + x1 * wa[1];
                ps[r * 1024 + o * 128 + jb + 64] = x0 * wa[2] + x1 * wa[3];
            }
            __syncthreads();
            for (int oi = T; oi < 8 * 128; oi += 512) {
                const int r = oi >> 7, j = oi & 127;
                float s = bias_l[j];
#pragma unroll
                for (int o2 = 0; o2 < 8; ++o2) s += ps[r * 1024 + o2 * 128 + j];
                bP[r * 128 + j] = fmaxf(s, 0.f);
            }
            __syncthreads();
            rstage<128, 128, 8, false>(wb, bP, 128, ps, bias_l + 128, bP);
            const int row0 = n0 + rb * 8;
            for (int oi = T; oi < 8 * 128; oi += 512) {
                const int r = oi >> 7, j = oi & 127;
                pu[(size_t)(row0 + r) * HH + j] = __float2bfloat16(bP[r * 128 + j]);
            }
            __syncthreads();
        }
    }
}

// ---------------------------------------------------------------------------
// Fused 2-layer GRU, 512 threads; lane-mapped k-slices (o = lane&3) with
// in-wave shfl reduction: o==0/1 lanes write FULL row sums to ps (6 KB),
// tail reads only 6 scalars per gate set. Skew: L0 at step i, L1 at i-1.
// 192 half2 weight regs/thread (partial AGPR banking accepted).
// ---------------------------------------------------------------------------
__device__ __forceinline__ void gmv_s(const half2v w[6][16], const _Float16* __restrict__ vb,
                                      int o, float* __restrict__ a)
{
    const half2v* vec2 = reinterpret_cast<const half2v*>(vb) + o * 16;
    a[0] = 0.f; a[1] = 0.f; a[2] = 0.f; a[3] = 0.f; a[4] = 0.f; a[5] = 0.f;
#pragma unroll
    for (int k4 = 0; k4 < 4; ++k4) {
        half2v xt[4];
        *reinterpret_cast<float4*>(xt) = reinterpret_cast<const float4*>(vec2)[k4];
#pragma unroll
        for (int e = 0; e < 4; ++e) {
            const int k = k4 * 4 + e;
            a[0] = __builtin_amdgcn_fdot2(xt[e], w[0][k], a[0], false);
            a[1] = __builtin_amdgcn_fdot2(xt[e], w[1][k], a[1], false);
            a[2] = __builtin_amdgcn_fdot2(xt[e], w[2][k], a[2], false);
            a[3] = __builtin_amdgcn_fdot2(xt[e], w[3][k], a[3], false);
            a[4] = __builtin_amdgcn_fdot2(xt[e], w[4][k], a[4], false);
            a[5] = __builtin_amdgcn_fdot2(xt[e], w[5][k], a[5], false);
        }
    }
#pragma unroll
    for (int j = 0; j < 6; ++j) {
        a[j] += __shfl_xor(a[j], 1, 64);
        a[j] += __shfl_xor(a[j], 2, 64);
    }
}

__global__ __launch_bounds__(512, 2) void gru_fused_kernel(
    const bf16* __restrict__ pu_in,   // (C*T, H)
    const float* __restrict__ wih,    // (L, 3H, H)
    const float* __restrict__ whh,    // (L, 3H, H)
    const float* __restrict__ h0_g,   // (L, B, H)
    bf16* __restrict__ hlast,         // (C*T, H)
    int s0)
{
    const int t = threadIdx.x;
    __shared__ __align__(16) _Float16 x0h[HH];
    __shared__ __align__(16) _Float16 x1h[2][HH];
    __shared__ __align__(16) _Float16 h0h[HH];
    __shared__ __align__(16) _Float16 h1h[HH];
    __shared__ __align__(16) float ps[2 * 768];

    const int lane = t & 63;
    const int o = lane & 3;
    const int r16 = lane >> 2;
    const int g = t >> 6;             // wave-uniform
    const int m = g >> 2, q = g & 3;
    const int rbase = r16 + 16 * q;   // rows rbase + 64*i6, i6 < 6
    const float* WbaseA = ((m == 0) ? wih : whh);
    const float* WbaseB = WbaseA + (size_t)H3 * HH;
    half2v wA[6][16], wB[6][16];
#pragma unroll
    for (int i6 = 0; i6 < 6; ++i6) {
        const float* sA = WbaseA + (size_t)(rbase + 64 * i6) * HH + o * 32;
        const float* sB = WbaseB + (size_t)(rbase + 64 * i6) * HH + o * 32;
#pragma unroll
        for (int k = 0; k < 16; ++k) {
            half2v v; v.x = (_Float16)sA[2 * k]; v.y = (_Float16)sA[2 * k + 1];
            wA[i6][k] = v;
            half2v u2; u2.x = (_Float16)sB[2 * k]; u2.y = (_Float16)sB[2 * k + 1];
            wB[i6][k] = u2;
        }
    }
    const int psb = m * 384 + rbase;

    const bf16* xb = pu_in + (size_t)blockIdx.x * TT * HH;
    bf16* ob = hlast + (size_t)blockIdx.x * TT * HH;

    float hreg = 0.f;                 // t<128: L0 state; t in [128,256): L1 state
    if (t < HH) {
        hreg = h0_g[(size_t)(s0 + blockIdx.x) * HH + t];
        h0h[t] = (_Float16)hreg;
        x0h[t] = (_Float16)__bfloat162float(xb[t]);
    } else if (t < 2 * HH) {
        const int j = t - HH;
        hreg = h0_g[((size_t)BB + s0 + blockIdx.x) * HH + j];
        h1h[j] = (_Float16)hreg;
    }
    __syncthreads();

#pragma unroll 1
    for (int i = 0; i <= TT; ++i) {
        float xnext = 0.f;
        if (t < HH && i + 1 < TT)
            xnext = __bfloat162float(xb[(size_t)(i + 1) * HH + t]);   // prefetch for L0
        float a[6], bv[6];
        if (i < TT)  gmv_s(wA, (m == 0) ? x0h : h0h, o, a);
        if (i >= 1)  gmv_s(wB, (m == 0) ? x1h[(i + 1) & 1] : h1h, o, bv);
        if (o < 2) {                  // distribute 6 full-row writes over 2 lanes
            const int base = psb + o * 192;   // rows +0/+64/+128 or +192/+256/+320
            const float v0 = o ? a[3] : a[0];
            const float v1 = o ? a[4] : a[1];
            const float v2 = o ? a[5] : a[2];
            const float u0 = o ? bv[3] : bv[0];
            const float u1 = o ? bv[4] : bv[1];
            const float u2 = o ? bv[5] : bv[2];
            if (i < TT) { ps[base] = v0; ps[base + 64] = v1; ps[base + 128] = v2; }
            if (i >= 1) { ps[768 + base] = u0; ps[768 + base + 64] = u1; ps[768 + base + 128] = u2; }
        }
        __syncthreads();   // ps ready; all LDS vec reads done
        if (t < HH) {
            if (i < TT) {
                const int j = t;
                const float gir = ps[j],       giz = ps[128 + j], gin = ps[256 + j];
                const float ghr = ps[384 + j], ghz = ps[512 + j], ghn = ps[640 + j];
                const float rg = 1.f / (1.f + __expf(-(gir + ghr)));
                const float zg = 1.f / (1.f + __expf(-(giz + ghz)));
                const float narg = gin + rg * ghn;
                const float e2 = __expf(2.f * fabsf(narg));
                float ng = 1.f - 2.f / (e2 + 1.f);
                ng = (narg < 0.f) ? -ng : ng;
                const float hn = (1.f - zg) * ng + zg * hreg;
                h0h[j] = (_Float16)hn;
                x1h[i & 1][j] = (_Float16)hn;   // L1 input for step i
                x0h[j] = (_Float16)xnext;
                hreg = hn;
            }
        } else if (t < 2 * HH) {
            if (i >= 1) {
                const int j = t - HH;
                const float gir = ps[768 + j],       giz = ps[896 + j], gin = ps[1024 + j];
                const float ghr = ps[1152 + j], ghz = ps[1280 + j], ghn = ps[1408 + j];
                const float rg = 1.f / (1.f + __expf(-(gir + ghr)));
                const float zg = 1.f / (1.f + __expf(-(giz + ghz)));
                const float narg = gin + rg * ghn;
                const float e2 = __expf(2.f * fabsf(narg));
                float ng = 1.f - 2.f / (e2 + 1.f);
                ng = (narg < 0.f) ? -ng : ng;
                ob[(size_t)(i - 1) * HH + j] = __float2bfloat16(hreg);  // pre-update
                const float hn = (1.f - zg) * ng + zg * hreg;
                h1h[j] = (_Float16)hn;
                hreg = hn;
            }
        }
        __syncthreads();   // h/x updated for next iteration
    }
}

// ---------------------------------------------------------------------------
// head v4: lane-mapped shfl-reduce stages, 1 barrier/stage, no ps (LDS ~11 KB).
// ---------------------------------------------------------------------------
__device__ __forceinline__ void stage_xc_h(_Float16* __restrict__ xc,
                                           const bf16* __restrict__ pu,
                                           const bf16* __restrict__ hl,
                                           int n0, int rb)
{
    const int T = threadIdx.x;
    const int base = n0 + rb * 8;
#pragma unroll
    for (int i = 0; i < 4; ++i) {
        const int idx = T + i * 512;
        const int r = idx >> 8, k = idx & 255;
        const size_t row = (size_t)(base + r);
        xc[r * 256 + k] = (_Float16)((k < 128) ? __bfloat162float(pu[row * HH + k])
                                               : __bfloat162float(hl[row * HH + (k - 128)]));
    }
}

__global__ __launch_bounds__(512, 2) void head_kernel(
    const bf16* __restrict__ pu, const bf16* __restrict__ hlast, const float* __restrict__ y_g,
    const float* __restrict__ dw1, const float* __restrict__ db1,
    const float* __restrict__ dw2, const float* __restrict__ db2,
    const float* __restrict__ xw, const float* __restrict__ xb,
    const float* __restrict__ pxw1, const float* __restrict__ pxb1,
    const float* __restrict__ pxw2, const float* __restrict__ pxb2,
    const float* __restrict__ mw1, const float* __restrict__ mb1,
    const float* __restrict__ mw2, const float* __restrict__ mb2,
    float* __restrict__ out, int s0, int nrows)
{
    __shared__ __align__(16) _Float16 xc[8 * 256];
    __shared__ __align__(16) _Float16 bP[8 * 128];
    __shared__ __align__(16) _Float16 bQ[8 * 128];
    __shared__ __align__(16) _Float16 bX[8 * 32];
    __shared__ __align__(16) float bias_l[688];
    __shared__ float red[8];
    const int T = threadIdx.x;

    if (T < 128) bias_l[T]       = db1[T];
    if (T < 128) bias_l[128 + T] = db2[T];
    if (T < 32)  bias_l[256 + T] = xb[T];
    if (T < 128) bias_l[288 + T] = pxb1[T];
    if (T < 128) bias_l[416 + T] = pxb2[T];
    if (T < 128) bias_l[544 + T] = mb1[T];
    if (T < 16)  bias_l[672 + T] = mb2[T];

    half2v w1[32]; loadw_s<128, 256, 8 >(w1, dw1);
    half2v w2[16]; loadw_s<128, 128, 8 >(w2, dw2);
    half2v w3[4];  loadw_s<32,  128, 32>(w3, xw);
    half2v w4[4];  loadw_s<128, 32,  8 >(w4, pxw1);
    half2v w5[16]; loadw_s<128, 128, 8 >(w5, pxw2);
    half2v w6[16]; loadw_s<128, 128, 8 >(w6, mw1);
    const int o7 = T & 63, j7 = T >> 6;   // S7: M=16, K=128, O=64, F=2
    half2v w7a, w7b;
    w7a.x = (_Float16)mw2[j7 * 128 + 2 * o7];
    w7a.y = (_Float16)mw2[j7 * 128 + 2 * o7 + 1];
    w7b.x = (_Float16)mw2[(j7 + 8) * 128 + 2 * o7];
    w7b.y = (_Float16)mw2[(j7 + 8) * 128 + 2 * o7 + 1];

    float lossreg = 0.f;

    for (int tile = blockIdx.x; tile < nrows / 32; tile += gridDim.x) {
        const int n0 = tile * 32;
        const int b  = s0 + (n0 >> 11);
        const int t0 = n0 & (TT - 1);
        stage_xc_h(xc, pu, hlast, n0, 0);
        __syncthreads();
#pragma unroll 1
        for (int rb = 0; rb < 4; ++rb) {
            rstage_s<128, 256, 8,  true >(w1, xc, 256, bias_l + 0,   bP);
            if (rb < 3) stage_xc_h(xc, pu, hlast, n0, rb + 1);       // xc free after S1
            rstage_s<128, 128, 8,  false>(w2, bP, 128, bias_l + 128, bQ);
            rstage_s<32,  128, 32, false>(w3, bQ, 128, bias_l + 256, bX);
            rstage_s<128, 32,  8,  true >(w4, bX, 32,  bias_l + 288, bP);
            rstage_s<128, 128, 8,  false>(w5, bP, 128, bias_l + 416, bQ);
            rstage_s<128, 128, 8,  true >(w6, bQ, 128, bias_l + 544, bP);
            // S7 + loss, fully in-wave
#pragma unroll
            for (int r = 0; r < 8; ++r) {
                const half2v xv = *reinterpret_cast<const half2v*>(&bP[r * 128 + 2 * o7]);
                float a0 = __builtin_amdgcn_fdot2(xv, w7a, 0.f, false);
                float a1 = __builtin_amdgcn_fdot2(xv, w7b, 0.f, false);
#pragma unroll
                for (int s = 1; s < 64; s <<= 1) {
                    a0 += __shfl_xor(a0, s, 64);
                    a1 += __shfl_xor(a1, s, 64);
                }
                if (o7 == 0) {
                    const int trow = t0 + rb * 8 + r;
                    const float y0 = y_g[((size_t)b * YDIM + j7) * TT + trow];
                    const float y1 = y_g[((size_t)b * YDIM + j7 + 8) * TT + trow];
                    const float d0 = a0 + bias_l[672 + j7] - y0;
                    const float d1 = a1 + bias_l[680 + j7] - y1;
                    lossreg += d0 * d0 + d1 * d1;
                }
            }
            __syncthreads();   // bP reads done before next S1 writes
        }
    }
#pragma unroll
    for (int off = 32; off > 0; off >>= 1) lossreg += __shfl_down(lossreg, off, 64);
    if ((T & 63) == 0) red[T >> 6] = lossreg;
    __syncthreads();
    if (T == 0) {
        float s = 0.f;
#pragma unroll
        for (int i = 0; i < 8; ++i) s += red[i];
        atomicAdd(out, s);
    }
}

__global__ void zero_out_kernel(float* o) { o[0] = 0.f; }

extern "C" void kernel_launch(void* const* d_in, const int* in_sizes, int n_in,
                              void* d_out, int out_size, void* d_ws, size_t ws_size,
                              hipStream_t stream)
{
    (void)in_sizes; (void)n_in; (void)out_size;
    const float* u    = (const float*)d_in[0];
    const float* y    = (const float*)d_in[1];
    const float* h0   = (const float*)d_in[2];
    const float* puw1 = (const float*)d_in[3];
    const float* pub1 = (const float*)d_in[4];
    const float* puw2 = (const float*)d_in[5];
    const float* pub2 = (const float*)d_in[6];
    const float* dw1  = (const float*)d_in[7];
    const float* db1  = (const float*)d_in[8];
    const float* dw2  = (const float*)d_in[9];
    const float* db2  = (const float*)d_in[10];
    const float* xw   = (const float*)d_in[11];
    const float* xbi  = (const float*)d_in[12];
    const float* pxw1 = (const float*)d_in[13];
    const float* pxb1 = (const float*)d_in[14];
    const float* pxw2 = (const float*)d_in[15];
    const float* pxb2 = (const float*)d_in[16];
    const float* mw1  = (const float*)d_in[17];
    const float* mb1  = (const float*)d_in[18];
    const float* mw2  = (const float*)d_in[19];
    const float* mb2  = (const float*)d_in[20];
    const float* gwih = (const float*)d_in[21];
    const float* gwhh = (const float*)d_in[22];

    const size_t per_sample = (size_t)TT * HH * 2 * 2;   // pu + hlast (bf16)
    int C = BB;
    while (C > 1 && (size_t)C * per_sample > ws_size) C >>= 1;
    bf16* puB = (bf16*)d_ws;
    bf16* hlB = puB + (size_t)C * TT * HH;

    zero_out_kernel<<<1, 1, 0, stream>>>((float*)d_out);
    for (int s0 = 0; s0 < BB; s0 += C) {
        phi_u_kernel<<<512, 512, 0, stream>>>(u, puw1, pub1, puw2, pub2, puB, s0, C * TT);
        gru_fused_kernel<<<C, 512, 0, stream>>>(puB, gwih, gwhh, h0, hlB, s0);
        head_kernel<<<512, 512, 0, stream>>>(puB, hlB, y,
                                             dw1, db1, dw2, db2, xw, xbi,
                                             pxw1, pxb1, pxw2, pxb2,
                                             mw1, mb1, mw2, mb2,
                                             (float*)d_out, s0, C * TT);
    }
}

// Round 16
// 4995.388 us; speedup vs baseline: 1.5760x; 1.5760x over previous
//
#include <hip/hip_runtime.h>
#include <hip/hip_bf16.h>

#define TT 2048
#define BB 256
#define HH 128
#define UDIM 16
#define YDIM 16
#define ZDIM 32
#define H3 384

typedef __hip_bfloat16 bf16;
typedef _Float16 half2v __attribute__((ext_vector_type(2)));

constexpr int clog2(int x) { return x <= 1 ? 0 : 1 + clog2(x >> 1); }

// ---------------------------------------------------------------------------
// f32 register-weight linear stage (phi_u only).
// ---------------------------------------------------------------------------
template <int M_, int K_, int O_, bool RELU_>
__device__ __forceinline__ void rstage(const float* __restrict__ wfrag,
                                       const float* __restrict__ xin, int XS,
                                       float* __restrict__ ps,
                                       const float* __restrict__ bias,
                                       float* __restrict__ outb)
{
    constexpr int F = K_ / O_;
    const int T = threadIdx.x;
    const int jb = T & (M_ / 2 - 1);
    const int o  = T >> clog2(M_ / 2);
#pragma unroll
    for (int r = 0; r < 8; ++r) {
        float a0 = 0.f, a1 = 0.f;
#pragma unroll
        for (int g = 0; g < F; g += 4) {
            const float4 xv = *reinterpret_cast<const float4*>(&xin[r * XS + o * F + g]);
            a0 += xv.x * wfrag[g]     + xv.y * wfrag[g + 1]
                + xv.z * wfrag[g + 2] + xv.w * wfrag[g + 3];
            a1 += xv.x * wfrag[F + g]     + xv.y * wfrag[F + g + 1]
                + xv.z * wfrag[F + g + 2] + xv.w * wfrag[F + g + 3];
        }
        ps[r * 1024 + o * M_ + jb]           = a0;
        ps[r * 1024 + o * M_ + jb + M_ / 2]  = a1;
    }
    __syncthreads();
    for (int oi = T; oi < 8 * M_; oi += 512) {
        const int r = oi >> clog2(M_);
        const int j = oi & (M_ - 1);
        float s = bias[j];
#pragma unroll
        for (int o2 = 0; o2 < O_; ++o2) s += ps[r * 1024 + o2 * M_ + j];
        if (RELU_) s = fmaxf(s, 0.f);
        outb[r * M_ + j] = s;
    }
    __syncthreads();
}

template <int M_, int K_, int O_>
__device__ __forceinline__ void loadw(float* __restrict__ wfrag, const float* __restrict__ Wg)
{
    constexpr int F = K_ / O_;
    const int T = threadIdx.x;
    const int jb = T & (M_ / 2 - 1);
    const int o  = T >> clog2(M_ / 2);
#pragma unroll
    for (int h = 0; h < 2; ++h)
#pragma unroll
        for (int g = 0; g < F; g += 4)
            *reinterpret_cast<float4*>(&wfrag[h * F + g]) =
                *reinterpret_cast<const float4*>(&Wg[(jb + h * (M_ / 2)) * K_ + o * F + g]);
}

// f16 variants (head): wfrag = F half2 (2 rows x F/2), xin f16 LDS, XS in halves.
template <int M_, int K_, int O_>
__device__ __forceinline__ void loadw_h(half2v* __restrict__ wfrag, const float* __restrict__ Wg)
{
    constexpr int F = K_ / O_;
    const int T = threadIdx.x;
    const int jb = T & (M_ / 2 - 1);
    const int o  = T >> clog2(M_ / 2);
#pragma unroll
    for (int h = 0; h < 2; ++h)
#pragma unroll
        for (int g = 0; g < F / 2; ++g) {
            const float* s = &Wg[(jb + h * (M_ / 2)) * K_ + o * F + 2 * g];
            half2v v; v.x = (_Float16)s[0]; v.y = (_Float16)s[1];
            wfrag[h * (F / 2) + g] = v;
        }
}

template <int M_, int K_, int O_, bool RELU_>
__device__ __forceinline__ void rstage_h(const half2v* __restrict__ wfrag,
                                         const _Float16* __restrict__ xin, int XS,
                                         float* __restrict__ ps,
                                         const float* __restrict__ bias,
                                         _Float16* __restrict__ outb)
{
    constexpr int F = K_ / O_;
    constexpr int FH = F / 2;
    const int T = threadIdx.x;
    const int jb = T & (M_ / 2 - 1);
    const int o  = T >> clog2(M_ / 2);
#pragma unroll
    for (int r = 0; r < 8; ++r) {
        float a0 = 0.f, a1 = 0.f;
        const half2v* xv = reinterpret_cast<const half2v*>(xin + r * XS + o * F);
        if constexpr (FH >= 4) {
#pragma unroll
            for (int g4 = 0; g4 < FH / 4; ++g4) {
                half2v xt[4];
                *reinterpret_cast<float4*>(xt) = reinterpret_cast<const float4*>(xv)[g4];
#pragma unroll
                for (int e = 0; e < 4; ++e) {
                    a0 = __builtin_amdgcn_fdot2(xt[e], wfrag[g4 * 4 + e], a0, false);
                    a1 = __builtin_amdgcn_fdot2(xt[e], wfrag[FH + g4 * 4 + e], a1, false);
                }
            }
        } else {   // FH == 2
            half2v xt[2];
            *reinterpret_cast<float2*>(xt) = *reinterpret_cast<const float2*>(xv);
            a0 = __builtin_amdgcn_fdot2(xt[0], wfrag[0], a0, false);
            a0 = __builtin_amdgcn_fdot2(xt[1], wfrag[1], a0, false);
            a1 = __builtin_amdgcn_fdot2(xt[0], wfrag[FH], a1, false);
            a1 = __builtin_amdgcn_fdot2(xt[1], wfrag[FH + 1], a1, false);
        }
        ps[r * 1024 + o * M_ + jb]           = a0;
        ps[r * 1024 + o * M_ + jb + M_ / 2]  = a1;
    }
    __syncthreads();
    for (int oi = T; oi < 8 * M_; oi += 512) {
        const int r = oi >> clog2(M_);
        const int j = oi & (M_ - 1);
        float s = bias[j];
#pragma unroll
        for (int o2 = 0; o2 < O_; ++o2) s += ps[r * 1024 + o2 * M_ + j];
        if (RELU_) s = fmaxf(s, 0.f);
        outb[r * M_ + j] = (_Float16)s;
    }
    __syncthreads();
}

// ---------------------------------------------------------------------------
// phi_u: register weights, persistent 512 blocks (unchanged).
// ---------------------------------------------------------------------------
__global__ __launch_bounds__(512, 2) void phi_u_kernel(
    const float* __restrict__ u, const float* __restrict__ w1, const float* __restrict__ b1,
    const float* __restrict__ w2, const float* __restrict__ b2,
    bf16* __restrict__ pu, int s0, int nrows)
{
    __shared__ __align__(16) float ps[8192];
    __shared__ __align__(16) float xc[8 * 16];
    __shared__ __align__(16) float bP[8 * 128];
    __shared__ __align__(16) float bias_l[256];
    const int T = threadIdx.x;
    if (T < 128) { bias_l[T] = b1[T]; bias_l[128 + T] = b2[T]; }
    const int jb = T & 63, o = T >> 6;
    float wa[4];
    wa[0] = w1[jb * 16 + o * 2];        wa[1] = w1[jb * 16 + o * 2 + 1];
    wa[2] = w1[(jb + 64) * 16 + o * 2]; wa[3] = w1[(jb + 64) * 16 + o * 2 + 1];
    float wb[32]; loadw<128, 128, 8>(wb, w2);
    __syncthreads();

    for (int tile = blockIdx.x; tile < nrows / 32; tile += gridDim.x) {
        const int n0 = tile * 32;
        const int b  = s0 + (n0 >> 11);
        const int t0 = n0 & (TT - 1);
#pragma unroll 1
        for (int rb = 0; rb < 4; ++rb) {
            if (T < 128) {
                const int r = T & 7, c = T >> 3;
                xc[r * 16 + c] = u[((size_t)b * UDIM + c) * TT + t0 + rb * 8 + r];
            }
            __syncthreads();
#pragma unroll
            for (int r = 0; r < 8; ++r) {
                const float x0 = xc[r * 16 + o * 2], x1 = xc[r * 16 + o * 2 + 1];
                ps[r * 1024 + o * 128 + jb]      = x0 * wa[0] + x1 * wa[1];
                ps[r * 1024 + o * 128 + jb + 64] = x0 * wa[2] + x1 * wa[3];
            }
            __syncthreads();
            for (int oi = T; oi < 8 * 128; oi += 512) {
                const int r = oi >> 7, j = oi & 127;
                float s = bias_l[j];
#pragma unroll
                for (int o2 = 0; o2 < 8; ++o2) s += ps[r * 1024 + o2 * 128 + j];
                bP[r * 128 + j] = fmaxf(s, 0.f);
            }
            __syncthreads();
            rstage<128, 128, 8, false>(wb, bP, 128, ps, bias_l + 128, bP);
            const int row0 = n0 + rb * 8;
            for (int oi = T; oi < 8 * 128; oi += 512) {
                const int r = oi >> 7, j = oi & 127;
                pu[(size_t)(row0 + r) * HH + j] = __float2bfloat16(bP[r * 128 + j]);
            }
            __syncthreads();
        }
    }
}

// ---------------------------------------------------------------------------
// Fused 2-layer GRU, 512 threads (round-12 structure), with
// amdgpu_waves_per_eu(2,2): pins the allocator budget to 256 arch VGPRs so
// the 192 half2 weights live architecturally (no AGPR copy per v_dot2).
// ---------------------------------------------------------------------------
__device__ __forceinline__ void gmv(const half2v w[6][16], const _Float16* __restrict__ vb,
                                    int o, float* __restrict__ psL, int psb)
{
    const half2v* vec2 = reinterpret_cast<const half2v*>(vb) + o * 16;
    float a0 = 0.f, a1 = 0.f, a2 = 0.f, a3 = 0.f, a4 = 0.f, a5 = 0.f;
#pragma unroll
    for (int k4 = 0; k4 < 4; ++k4) {
        half2v xt[4];
        *reinterpret_cast<float4*>(xt) = reinterpret_cast<const float4*>(vec2)[k4];
#pragma unroll
        for (int e = 0; e < 4; ++e) {
            const int k = k4 * 4 + e;
            a0 = __builtin_amdgcn_fdot2(xt[e], w[0][k], a0, false);
            a1 = __builtin_amdgcn_fdot2(xt[e], w[1][k], a1, false);
            a2 = __builtin_amdgcn_fdot2(xt[e], w[2][k], a2, false);
            a3 = __builtin_amdgcn_fdot2(xt[e], w[3][k], a3, false);
            a4 = __builtin_amdgcn_fdot2(xt[e], w[4][k], a4, false);
            a5 = __builtin_amdgcn_fdot2(xt[e], w[5][k], a5, false);
        }
    }
    psL[psb]       = a0; psL[psb + 64]  = a1; psL[psb + 128] = a2;
    psL[psb + 192] = a3; psL[psb + 256] = a4; psL[psb + 320] = a5;
}

__global__ __launch_bounds__(512)
__attribute__((amdgpu_waves_per_eu(2, 2)))
void gru_fused_kernel(
    const bf16* __restrict__ pu_in,   // (C*T, H)
    const float* __restrict__ wih,    // (L, 3H, H)
    const float* __restrict__ whh,    // (L, 3H, H)
    const float* __restrict__ h0_g,   // (L, B, H)
    bf16* __restrict__ hlast,         // (C*T, H)
    int s0)
{
    const int t = threadIdx.x;
    __shared__ __align__(16) _Float16 x0h[HH];
    __shared__ __align__(16) _Float16 x1h[2][HH];
    __shared__ __align__(16) _Float16 h0h[HH];
    __shared__ __align__(16) _Float16 h1h[HH];
    __shared__ __align__(16) float ps[2 * 3072];

    const int g = t >> 6;             // wave-uniform
    const int m = g >> 2, o = g & 3;
    const int u = t & 63;
    const float* WbaseA = ((m == 0) ? wih : whh);
    const float* WbaseB = WbaseA + (size_t)H3 * HH;
    half2v wA[6][16], wB[6][16];
#pragma unroll
    for (int i = 0; i < 6; ++i) {
        const float* sA = &WbaseA[(u + 64 * i) * HH + o * 32];
        const float* sB = &WbaseB[(u + 64 * i) * HH + o * 32];
#pragma unroll
        for (int k = 0; k < 16; ++k) {
            half2v v; v.x = (_Float16)sA[2 * k]; v.y = (_Float16)sA[2 * k + 1];
            wA[i][k] = v;
            half2v w2; w2.x = (_Float16)sB[2 * k]; w2.y = (_Float16)sB[2 * k + 1];
            wB[i][k] = w2;
        }
    }
    float* psA = ps;
    float* psB = ps + 3072;
    const int psb = o * 768 + m * 384 + u;

    const bf16* xb = pu_in + (size_t)blockIdx.x * TT * HH;
    bf16* ob = hlast + (size_t)blockIdx.x * TT * HH;

    float hreg = 0.f;                 // t<128: L0 state; t in [128,256): L1 state
    if (t < HH) {
        hreg = h0_g[(size_t)(s0 + blockIdx.x) * HH + t];
        h0h[t] = (_Float16)hreg;
        x0h[t] = (_Float16)__bfloat162float(xb[t]);
    } else if (t < 2 * HH) {
        const int j = t - HH;
        hreg = h0_g[((size_t)BB + s0 + blockIdx.x) * HH + j];
        h1h[j] = (_Float16)hreg;
    }
    __syncthreads();

#pragma unroll 1
    for (int i = 0; i <= TT; ++i) {
        float xnext = 0.f;
        if (t < HH && i + 1 < TT)
            xnext = __bfloat162float(xb[(size_t)(i + 1) * HH + t]);   // prefetch for L0
        if (i < TT)  gmv(wA, (m == 0) ? x0h : h0h, o, psA, psb);
        if (i >= 1)  gmv(wB, (m == 0) ? x1h[(i + 1) & 1] : h1h, o, psB, psb);
        __syncthreads();   // ps ready; all LDS vec reads done
        if (t < HH) {
            if (i < TT) {
                const int j = t;
                float gir = 0.f, giz = 0.f, gin = 0.f, ghr = 0.f, ghz = 0.f, ghn = 0.f;
#pragma unroll
                for (int o2 = 0; o2 < 4; ++o2) {
                    const float* pp = psA + o2 * 768;
                    gir += pp[j];        giz += pp[128 + j]; gin += pp[256 + j];
                    ghr += pp[384 + j];  ghz += pp[512 + j]; ghn += pp[640 + j];
                }
                const float rg = 1.f / (1.f + __expf(-(gir + ghr)));
                const float zg = 1.f / (1.f + __expf(-(giz + ghz)));
                const float narg = gin + rg * ghn;
                const float e2 = __expf(2.f * fabsf(narg));
                float ng = 1.f - 2.f / (e2 + 1.f);
                ng = (narg < 0.f) ? -ng : ng;
                const float hn = (1.f - zg) * ng + zg * hreg;
                h0h[j] = (_Float16)hn;
                x1h[i & 1][j] = (_Float16)hn;   // L1 input for step i
                x0h[j] = (_Float16)xnext;
                hreg = hn;
            }
        } else if (t < 2 * HH) {
            if (i >= 1) {
                const int j = t - HH;
                float gir = 0.f, giz = 0.f, gin = 0.f, ghr = 0.f, ghz = 0.f, ghn = 0.f;
#pragma unroll
                for (int o2 = 0; o2 < 4; ++o2) {
                    const float* pp = psB + o2 * 768;
                    gir += pp[j];        giz += pp[128 + j]; gin += pp[256 + j];
                    ghr += pp[384 + j];  ghz += pp[512 + j]; ghn += pp[640 + j];
                }
                const float rg = 1.f / (1.f + __expf(-(gir + ghr)));
                const float zg = 1.f / (1.f + __expf(-(giz + ghz)));
                const float narg = gin + rg * ghn;
                const float e2 = __expf(2.f * fabsf(narg));
                float ng = 1.f - 2.f / (e2 + 1.f);
                ng = (narg < 0.f) ? -ng : ng;
                ob[(size_t)(i - 1) * HH + j] = __float2bfloat16(hreg);  // pre-update
                const float hn = (1.f - zg) * ng + zg * hreg;
                h1h[j] = (_Float16)hn;
                hreg = hn;
            }
        }
        __syncthreads();   // h/x updated for next iteration
    }
}

// ---------------------------------------------------------------------------
// head v3 (round-12 proven): f16 dot2 stages, ps-based partials.
// amdgpu_waves_per_eu(4,4): demand ~110 regs -> cap 128 -> 2 blocks/CU.
// ---------------------------------------------------------------------------
__device__ __forceinline__ void stage_xc_h(_Float16* __restrict__ xc,
                                           const bf16* __restrict__ pu,
                                           const bf16* __restrict__ hl,
                                           int n0, int rb)
{
    const int T = threadIdx.x;
    const int base = n0 + rb * 8;
#pragma unroll
    for (int i = 0; i < 4; ++i) {
        const int idx = T + i * 512;
        const int r = idx >> 8, k = idx & 255;
        const size_t row = (size_t)(base + r);
        xc[r * 256 + k] = (_Float16)((k < 128) ? __bfloat162float(pu[row * HH + k])
                                               : __bfloat162float(hl[row * HH + (k - 128)]));
    }
}

__global__ __launch_bounds__(512)
__attribute__((amdgpu_waves_per_eu(4, 4)))
void head_kernel(
    const bf16* __restrict__ pu, const bf16* __restrict__ hlast, const float* __restrict__ y_g,
    const float* __restrict__ dw1, const float* __restrict__ db1,
    const float* __restrict__ dw2, const float* __restrict__ db2,
    const float* __restrict__ xw, const float* __restrict__ xb,
    const float* __restrict__ pxw1, const float* __restrict__ pxb1,
    const float* __restrict__ pxw2, const float* __restrict__ pxb2,
    const float* __restrict__ mw1, const float* __restrict__ mb1,
    const float* __restrict__ mw2, const float* __restrict__ mb2,
    float* __restrict__ out, int s0, int nrows)
{
    __shared__ __align__(16) float ps[8192];
    __shared__ __align__(16) _Float16 xc[8 * 256];
    __shared__ __align__(16) _Float16 bP[8 * 128];
    __shared__ __align__(16) _Float16 bQ[8 * 128];
    __shared__ __align__(16) _Float16 bX[8 * 32];
    __shared__ __align__(16) float bias_l[688];
    __shared__ float red[8];
    const int T = threadIdx.x;

    if (T < 128) bias_l[T]       = db1[T];
    if (T < 128) bias_l[128 + T] = db2[T];
    if (T < 32)  bias_l[256 + T] = xb[T];
    if (T < 128) bias_l[288 + T] = pxb1[T];
    if (T < 128) bias_l[416 + T] = pxb2[T];
    if (T < 128) bias_l[544 + T] = mb1[T];
    if (T < 16)  bias_l[672 + T] = mb2[T];

    half2v w1[32]; loadw_h<128, 256, 8 >(w1, dw1);
    half2v w2[16]; loadw_h<128, 128, 8 >(w2, dw2);
    half2v w3[4];  loadw_h<32,  128, 32>(w3, xw);
    half2v w4[4];  loadw_h<128, 32,  8 >(w4, pxw1);
    half2v w5[16]; loadw_h<128, 128, 8 >(w5, pxw2);
    half2v w6[16]; loadw_h<128, 128, 8 >(w6, mw1);
    const int jb7 = T & 7, o7 = T >> 3;   // S7: M=16,K=128,O=64,F=2
    half2v w7a, w7b;
    w7a.x = (_Float16)mw2[jb7 * 128 + 2 * o7];
    w7a.y = (_Float16)mw2[jb7 * 128 + 2 * o7 + 1];
    w7b.x = (_Float16)mw2[(jb7 + 8) * 128 + 2 * o7];
    w7b.y = (_Float16)mw2[(jb7 + 8) * 128 + 2 * o7 + 1];

    float lossreg = 0.f;

    for (int tile = blockIdx.x; tile < nrows / 32; tile += gridDim.x) {
        const int n0 = tile * 32;
        const int b  = s0 + (n0 >> 11);
        const int t0 = n0 & (TT - 1);
        stage_xc_h(xc, pu, hlast, n0, 0);
#pragma unroll 1
        for (int rb = 0; rb < 4; ++rb) {
            __syncthreads();   // xc ready; ps free from previous batch
            rstage_h<128, 256, 8,  true >(w1, xc, 256, ps, bias_l + 0,   bP);
            rstage_h<128, 128, 8,  false>(w2, bP, 128, ps, bias_l + 128, bQ);
            rstage_h<32,  128, 32, false>(w3, bQ, 128, ps, bias_l + 256, bX);
            rstage_h<128, 32,  8,  true >(w4, bX, 32,  ps, bias_l + 288, bP);
            rstage_h<128, 128, 8,  false>(w5, bP, 128, ps, bias_l + 416, bQ);
            rstage_h<128, 128, 8,  true >(w6, bQ, 128, ps, bias_l + 544, bP);
            // S7 partials (dot2) + prefetch next batch's xc
#pragma unroll
            for (int r = 0; r < 8; ++r) {
                const half2v xv = *reinterpret_cast<const half2v*>(&bP[r * 128 + 2 * o7]);
                ps[r * 1024 + o7 * 16 + jb7]     = __builtin_amdgcn_fdot2(xv, w7a, 0.f, false);
                ps[r * 1024 + o7 * 16 + jb7 + 8] = __builtin_amdgcn_fdot2(xv, w7b, 0.f, false);
            }
            if (rb < 3) stage_xc_h(xc, pu, hlast, n0, rb + 1);
            __syncthreads();
            if (T < 128) {
                const int r = T >> 4, j = T & 15;
                float s = bias_l[672 + j];
#pragma unroll
                for (int o2 = 0; o2 < 64; ++o2) s += ps[r * 1024 + o2 * 16 + j];
                const int trow = t0 + rb * 8 + r;
                const float yv = y_g[((size_t)b * YDIM + j) * TT + trow];
                const float d = s - yv;
                lossreg += d * d;
            }
            // loop-top barrier closes this batch
        }
    }
    __syncthreads();
#pragma unroll
    for (int off = 32; off > 0; off >>= 1) lossreg += __shfl_down(lossreg, off, 64);
    if ((T & 63) == 0) red[T >> 6] = lossreg;
    __syncthreads();
    if (T == 0) {
        float s = 0.f;
#pragma unroll
        for (int i = 0; i < 8; ++i) s += red[i];
        atomicAdd(out, s);
    }
}

__global__ void zero_out_kernel(float* o) { o[0] = 0.f; }

extern "C" void kernel_launch(void* const* d_in, const int* in_sizes, int n_in,
                              void* d_out, int out_size, void* d_ws, size_t ws_size,
                              hipStream_t stream)
{
    (void)in_sizes; (void)n_in; (void)out_size;
    const float* u    = (const float*)d_in[0];
    const float* y    = (const float*)d_in[1];
    const float* h0   = (const float*)d_in[2];
    const float* puw1 = (const float*)d_in[3];
    const float* pub1 = (const float*)d_in[4];
    const float* puw2 = (const float*)d_in[5];
    const float* pub2 = (const float*)d_in[6];
    const float* dw1  = (const float*)d_in[7];
    const float* db1  = (const float*)d_in[8];
    const float* dw2  = (const float*)d_in[9];
    const float* db2  = (const float*)d_in[10];
    const float* xw   = (const float*)d_in[11];
    const float* xbi  = (const float*)d_in[12];
    const float* pxw1 = (const float*)d_in[13];
    const float* pxb1 = (const float*)d_in[14];
    const float* pxw2 = (const float*)d_in[15];
    const float* pxb2 = (const float*)d_in[16];
    const float* mw1  = (const float*)d_in[17];
    const float* mb1  = (const float*)d_in[18];
    const float* mw2  = (const float*)d_in[19];
    const float* mb2  = (const float*)d_in[20];
    const float* gwih = (const float*)d_in[21];
    const float* gwhh = (const float*)d_in[22];

    const size_t per_sample = (size_t)TT * HH * 2 * 2;   // pu + hlast (bf16)
    int C = BB;
    while (C > 1 && (size_t)C * per_sample > ws_size) C >>= 1;
    bf16* puB = (bf16*)d_ws;
    bf16* hlB = puB + (size_t)C * TT * HH;

    zero_out_kernel<<<1, 1, 0, stream>>>((float*)d_out);
    for (int s0 = 0; s0 < BB; s0 += C) {
        phi_u_kernel<<<512, 512, 0, stream>>>(u, puw1, pub1, puw2, pub2, puB, s0, C * TT);
        gru_fused_kernel<<<C, 512, 0, stream>>>(puB, gwih, gwhh, h0, hlB, s0);
        head_kernel<<<512, 512, 0, stream>>>(puB, hlB, y,
                                             dw1, db1, dw2, db2, xw, xbi,
                                             pxw1, pxb1, pxw2, pxb2,
                                             mw1, mb1, mw2, mb2,
                                             (float*)d_out, s0, C * TT);
    }
}